// Round 1
// baseline (436.090 us; speedup 1.0000x reference)
//
#include <hip/hip_runtime.h>

#define NN 100000
#define NE 1000000
#define BSH 7        // bucket shift: 128 cols per bucket
#define BCOLS 128
#define NBUCK 782    // ceil(NN / 128)
#define SBLK 128     // scatter/hist blocks (edge partition)
#define STHR 256
#define AGG_THR 256

// ---------------------------------------------------------------------------
// K_f: fuse the whole linear chain into Mt[128][24]:
//   Mt[k][0..20]  = fused GCN->layer1 matrix column k ( [Wu@W1_top; Wm@W1_bot] )
//   Mt[k][21]     = b1'[k] = b1[k] + bu@W1_top[:,k] + bm@W1_bot[:,k]
//   Mt[k][22]     = W2[k]
// ---------------------------------------------------------------------------
__global__ __launch_bounds__(128) void fuse_kernel(const float* __restrict__ Wu,
                                                   const float* __restrict__ bu,
                                                   const float* __restrict__ Wm,
                                                   const float* __restrict__ bm,
                                                   const float* __restrict__ W1,
                                                   const float* __restrict__ b1,
                                                   const float* __restrict__ W2,
                                                   float* __restrict__ Mt) {
    const int j = threadIdx.x;
    float w1c[128];
#pragma unroll
    for (int k = 0; k < 128; k++) w1c[k] = W1[k * 128 + j];

    float* row = Mt + j * 24;
#pragma unroll
    for (int m = 0; m < 3; m++) {
        float acc = 0.f;
#pragma unroll
        for (int k = 0; k < 64; k++) acc = fmaf(Wu[m * 64 + k], w1c[k], acc);
        row[m] = acc;
    }
#pragma unroll
    for (int m = 0; m < 18; m++) {
        float acc = 0.f;
#pragma unroll
        for (int k = 0; k < 64; k++) acc = fmaf(Wm[m * 64 + k], w1c[64 + k], acc);
        row[3 + m] = acc;
    }
    float bp = b1[j];
#pragma unroll
    for (int k = 0; k < 64; k++) {
        bp = fmaf(bu[k], w1c[k], bp);
        bp = fmaf(bm[k], w1c[64 + k], bp);
    }
    row[21] = bp;
    row[22] = W2[j];
    row[23] = 0.f;
}

// ---------------------------------------------------------------------------
// K_a: per-(block,bucket) histogram. No global atomics.
// ---------------------------------------------------------------------------
__global__ __launch_bounds__(STHR) void bhist_kernel(const int* __restrict__ col,
                                                     int* __restrict__ H) {
    __shared__ int h[NBUCK];
    for (int i = threadIdx.x; i < NBUCK; i += STHR) h[i] = 0;
    __syncthreads();
    for (int e = blockIdx.x * STHR + threadIdx.x; e < NE; e += SBLK * STHR)
        atomicAdd(&h[col[e] >> BSH], 1);
    __syncthreads();
    for (int b = threadIdx.x; b < NBUCK; b += STHR)
        H[b * SBLK + blockIdx.x] = h[b];
}

// ---------------------------------------------------------------------------
// K_b: exclusive scan of H (NBUCK*SBLK = 100096 ints) in one block.
// ---------------------------------------------------------------------------
__global__ __launch_bounds__(1024) void bscan_kernel(int* __restrict__ H) {
    const int TOT = NBUCK * SBLK;          // 100096
    const int PER = 98;                    // 1024*98 >= TOT
    const int t = threadIdx.x;
    const int base = t * PER;
    int v[PER];
    int sum = 0;
#pragma unroll
    for (int i = 0; i < PER; i++) {
        int idx = base + i;
        v[i] = (idx < TOT) ? H[idx] : 0;
        sum += v[i];
    }
    __shared__ int s[1024];
    s[t] = sum;
    __syncthreads();
    for (int off = 1; off < 1024; off <<= 1) {
        int x = (t >= off) ? s[t - off] : 0;
        __syncthreads();
        s[t] += x;
        __syncthreads();
    }
    int run = s[t] - sum;
#pragma unroll
    for (int i = 0; i < PER; i++) {
        int idx = base + i;
        if (idx < TOT) H[idx] = run;
        run += v[i];
    }
}

// ---------------------------------------------------------------------------
// K_c: deterministic scatter into per-(bucket,block) runs. No global atomics.
// Payload: x = (col&127) | (row<<7)  (17+7=24 bits), y = ew bits.
// ---------------------------------------------------------------------------
__global__ __launch_bounds__(STHR) void bscatter_kernel(const int* __restrict__ ei,
                                                        const float* __restrict__ ew,
                                                        const int* __restrict__ H,
                                                        int2* __restrict__ mid) {
    __shared__ int rbase[NBUCK];
    __shared__ int rcnt[NBUCK];
    for (int i = threadIdx.x; i < NBUCK; i += STHR) {
        rbase[i] = H[i * SBLK + blockIdx.x];
        rcnt[i] = 0;
    }
    __syncthreads();
    for (int e = blockIdx.x * STHR + threadIdx.x; e < NE; e += SBLK * STHR) {
        const int c = ei[NE + e];
        const int r = ei[e];
        const float w = ew[e];
        const int b = c >> BSH;
        const int pos = rbase[b] + atomicAdd(&rcnt[b], 1);
        mid[pos] = make_int2((c & (BCOLS - 1)) | (r << BSH), __float_as_int(w));
    }
}

// ---------------------------------------------------------------------------
// K_d: fused per-bucket degree + row packing.
//   dinv = rsqrt(deg + 1) for the bucket's cols (== its rows),
//   pack[r][0..20] = dinv[r] * {ux[r], mx[r]},  pack[r][21] = dinv[r].
// 96 B rows, 16B-aligned -> one 2-line gather per edge downstream.
// ---------------------------------------------------------------------------
__global__ __launch_bounds__(256) void bdeg_pack_kernel(const int2* __restrict__ mid,
                                                        const int* __restrict__ H,
                                                        const float* __restrict__ ux,
                                                        const float* __restrict__ mx,
                                                        float* __restrict__ pack) {
    __shared__ float dl[BCOLS];
    const int b = blockIdx.x;
    const int t = threadIdx.x;
    if (t < BCOLS) dl[t] = 0.f;
    __syncthreads();
    const int start = H[b * SBLK];
    const int end = (b + 1 < NBUCK) ? H[(b + 1) * SBLK] : NE;
    for (int i = start + t; i < end; i += 256) {
        const int2 p = mid[i];
        atomicAdd(&dl[p.x & (BCOLS - 1)], __int_as_float(p.y));
    }
    __syncthreads();
    if (t < BCOLS) {
        const int c = b * BCOLS + t;
        if (c < NN) dl[t] = rsqrtf(dl[t] + 1.0f);
    }
    __syncthreads();
    // pack the bucket's rows; flat index -> fully coalesced 96B-row writes
    const size_t obase = (size_t)b * BCOLS * 24;
    for (int f = t; f < BCOLS * 24; f += 256) {
        const int rl = f / 24;
        const int m = f - rl * 24;
        const int r = b * BCOLS + rl;
        if (r < NN) {
            const float d = dl[rl];
            float v;
            if (m < 3) v = d * ux[(size_t)r * 3 + m];
            else if (m < 21) v = d * mx[(size_t)r * 18 + (m - 3)];
            else if (m == 21) v = d;
            else v = 0.f;
            pack[obase + f] = v;
        }
    }
}

// ---------------------------------------------------------------------------
// K_e: edge-parallel LDS-atomic aggregation + fused MLP. One block of 256
// threads per 128-col bucket. No sort, single mid pass, independent edge
// iterations (full MLP). MLP k-splits across thread halves.
// ---------------------------------------------------------------------------
__global__ __launch_bounds__(AGG_THR) void bagg_mlp_kernel(const int2* __restrict__ mid,
                                                           const int* __restrict__ H,
                                                           const float* __restrict__ pack,
                                                           const float* __restrict__ Mt,
                                                           const float* __restrict__ b2,
                                                           float* __restrict__ out) {
    __shared__ float s[BCOLS * 21];    // 10752 B accumulator (stride 21: odd -> conflict-free)
    __shared__ float po[BCOLS];        // MLP half-1 partials

    const int b = blockIdx.x;
    const int t = threadIdx.x;

    for (int i = t; i < BCOLS * 21; i += AGG_THR) s[i] = 0.f;
    __syncthreads();

    const int start = H[b * SBLK];
    const int end = (b + 1 < NBUCK) ? H[(b + 1) * SBLK] : NE;

#pragma unroll 2
    for (int i = start + t; i < end; i += AGG_THR) {
        const int2 p = mid[i];
        const int cl = p.x & (BCOLS - 1);
        const int row = ((unsigned)p.x) >> BSH;
        const float w = __int_as_float(p.y);
        const float4* pr = (const float4*)(pack + (size_t)row * 24);
        const float4 q0 = pr[0];
        const float4 q1 = pr[1];
        const float4 q2 = pr[2];
        const float4 q3 = pr[3];
        const float4 q4 = pr[4];
        const float f20 = pack[(size_t)row * 24 + 20];
        float* sb = s + cl * 21;
        atomicAdd(sb + 0,  w * q0.x);
        atomicAdd(sb + 1,  w * q0.y);
        atomicAdd(sb + 2,  w * q0.z);
        atomicAdd(sb + 3,  w * q0.w);
        atomicAdd(sb + 4,  w * q1.x);
        atomicAdd(sb + 5,  w * q1.y);
        atomicAdd(sb + 6,  w * q1.z);
        atomicAdd(sb + 7,  w * q1.w);
        atomicAdd(sb + 8,  w * q2.x);
        atomicAdd(sb + 9,  w * q2.y);
        atomicAdd(sb + 10, w * q2.z);
        atomicAdd(sb + 11, w * q2.w);
        atomicAdd(sb + 12, w * q3.x);
        atomicAdd(sb + 13, w * q3.y);
        atomicAdd(sb + 14, w * q3.z);
        atomicAdd(sb + 15, w * q3.w);
        atomicAdd(sb + 16, w * q4.x);
        atomicAdd(sb + 17, w * q4.y);
        atomicAdd(sb + 18, w * q4.z);
        atomicAdd(sb + 19, w * q4.w);
        atomicAdd(sb + 20, w * f20);
    }
    __syncthreads();

    // finalize per col: out_feat = dinv[c] * (sum + p[c])
    if (t < BCOLS) {
        const int c = b * BCOLS + t;
        if (c < NN) {
            const float4* pr = (const float4*)(pack + (size_t)c * 24);
            const float4 q0 = pr[0];
            const float4 q1 = pr[1];
            const float4 q2 = pr[2];
            const float4 q3 = pr[3];
            const float4 q4 = pr[4];
            const float4 q5 = pr[5];
            const float d = q5.y;          // dinv[c]
            float* sb = s + t * 21;
            sb[0]  = d * (sb[0]  + q0.x);
            sb[1]  = d * (sb[1]  + q0.y);
            sb[2]  = d * (sb[2]  + q0.z);
            sb[3]  = d * (sb[3]  + q0.w);
            sb[4]  = d * (sb[4]  + q1.x);
            sb[5]  = d * (sb[5]  + q1.y);
            sb[6]  = d * (sb[6]  + q1.z);
            sb[7]  = d * (sb[7]  + q1.w);
            sb[8]  = d * (sb[8]  + q2.x);
            sb[9]  = d * (sb[9]  + q2.y);
            sb[10] = d * (sb[10] + q2.z);
            sb[11] = d * (sb[11] + q2.w);
            sb[12] = d * (sb[12] + q3.x);
            sb[13] = d * (sb[13] + q3.y);
            sb[14] = d * (sb[14] + q3.z);
            sb[15] = d * (sb[15] + q3.w);
            sb[16] = d * (sb[16] + q4.x);
            sb[17] = d * (sb[17] + q4.y);
            sb[18] = d * (sb[18] + q4.z);
            sb[19] = d * (sb[19] + q4.w);
            sb[20] = d * (sb[20] + q5.x);
        }
    }
    __syncthreads();

    // fused MLP, k split across thread halves (half is wave-uniform: wave=64)
    const int col = t & (BCOLS - 1);
    const int half = t >> 7;
    float s21[21];
    const float* sb = s + col * 21;
#pragma unroll
    for (int m = 0; m < 21; m++) s21[m] = sb[m];
    float o = 0.f;
    const int k0 = half * 64;
#pragma unroll 4
    for (int k = k0; k < k0 + 64; k++) {
        const float* r = Mt + k * 24;
        float h = r[21];
#pragma unroll
        for (int m = 0; m < 21; m++) h = fmaf(s21[m], r[m], h);
        o = fmaf(fmaxf(h, 0.f), r[22], o);
    }
    if (half) po[col] = o;
    __syncthreads();
    if (!half) {
        const int c = b * BCOLS + col;
        if (c < NN) out[c] = o + po[col] + b2[0];
    }
}

// ===========================================================================
extern "C" void kernel_launch(void* const* d_in, const int* in_sizes, int n_in,
                              void* d_out, int out_size, void* d_ws, size_t ws_size,
                              hipStream_t stream) {
    const float* ux = (const float*)d_in[0];   // user_x  [N,3]
    const float* mx = (const float*)d_in[1];   // movie_x [N,18]
    const int* ei = (const int*)d_in[2];       // edge_index [2,E] (int32)
    const float* ew = (const float*)d_in[3];   // edge_attr [E]
    const float* Wu = (const float*)d_in[4];   // [3,64]
    const float* bu = (const float*)d_in[5];   // [64]
    const float* Wm = (const float*)d_in[6];   // [18,64]
    const float* bm = (const float*)d_in[7];   // [64]
    const float* W1 = (const float*)d_in[8];   // [128,128]
    const float* b1 = (const float*)d_in[9];   // [128]
    const float* W2 = (const float*)d_in[10];  // [128,1]
    const float* b2 = (const float*)d_in[11];  // [1]
    float* out = (float*)d_out;

    char* ws = (char*)d_ws;
    int*   H    = (int*)ws;                          // 100096*4 = 400,384 B
    float* Mt   = (float*)(ws + 400384);             // 128*24*4 = 12,288 B
    float* pack = (float*)(ws + 412672);             // NN*24*4 = 9,600,000 B (16B-aligned)
    int2*  mid  = (int2*)(ws + 10012672);            // NE*8 = 8,000,000 B
    // total ~18.0 MB; no memsets needed

    fuse_kernel<<<1, 128, 0, stream>>>(Wu, bu, Wm, bm, W1, b1, W2, Mt);
    bhist_kernel<<<SBLK, STHR, 0, stream>>>(ei + NE, H);
    bscan_kernel<<<1, 1024, 0, stream>>>(H);
    bscatter_kernel<<<SBLK, STHR, 0, stream>>>(ei, ew, H, mid);
    bdeg_pack_kernel<<<NBUCK, 256, 0, stream>>>(mid, H, ux, mx, pack);
    bagg_mlp_kernel<<<NBUCK, AGG_THR, 0, stream>>>(mid, H, pack, Mt, b2, out);
}

// Round 2
// 211.861 us; speedup vs baseline: 2.0584x; 2.0584x over previous
//
#include <hip/hip_runtime.h>

#define NN 100000
#define NE 1000000
#define BSH 7        // bucket shift: 128 cols per bucket
#define BCOLS 128
#define NBUCK 782    // ceil(NN / 128)
#define SBLK 256     // edge-partition blocks for count/scatter
#define CAP 2048     // max edges/bucket via LDS path (mean 1279, sigma ~36)

// ---------------------------------------------------------------------------
// K_f: fuse the whole linear chain into Mt[128][24]:
//   Mt[k][0..20] = fused GCN->layer1 matrix column k ( [Wu@W1_top; Wm@W1_bot] )
//   Mt[k][21]    = b1'[k],  Mt[k][22] = W2[k]
// Also zeroes cnt[] (runs before bcnt on the same stream).
// ---------------------------------------------------------------------------
__global__ __launch_bounds__(128) void fuse_kernel(const float* __restrict__ Wu,
                                                   const float* __restrict__ bu,
                                                   const float* __restrict__ Wm,
                                                   const float* __restrict__ bm,
                                                   const float* __restrict__ W1,
                                                   const float* __restrict__ b1,
                                                   const float* __restrict__ W2,
                                                   float* __restrict__ Mt,
                                                   int* __restrict__ cnt) {
    const int j = threadIdx.x;
    for (int i = j; i < NBUCK; i += 128) cnt[i] = 0;

    float w1c[128];
#pragma unroll
    for (int k = 0; k < 128; k++) w1c[k] = W1[k * 128 + j];

    float* row = Mt + j * 24;
#pragma unroll
    for (int m = 0; m < 3; m++) {
        float acc = 0.f;
#pragma unroll
        for (int k = 0; k < 64; k++) acc = fmaf(Wu[m * 64 + k], w1c[k], acc);
        row[m] = acc;
    }
#pragma unroll
    for (int m = 0; m < 18; m++) {
        float acc = 0.f;
#pragma unroll
        for (int k = 0; k < 64; k++) acc = fmaf(Wm[m * 64 + k], w1c[64 + k], acc);
        row[3 + m] = acc;
    }
    float bp = b1[j];
#pragma unroll
    for (int k = 0; k < 64; k++) {
        bp = fmaf(bu[k], w1c[k], bp);
        bp = fmaf(bm[k], w1c[64 + k], bp);
    }
    row[21] = bp;
    row[22] = W2[j];
    row[23] = 0.f;
}

// ---------------------------------------------------------------------------
// K_a: bucket counts. Per-block LDS histogram, then one global atomicAdd per
// (block,bucket) -- ~200K low-contention atomics, no 100K-element scan later.
// ---------------------------------------------------------------------------
__global__ __launch_bounds__(256) void bcnt_kernel(const int* __restrict__ col,
                                                   int* __restrict__ cnt) {
    __shared__ int h[NBUCK];
    for (int i = threadIdx.x; i < NBUCK; i += 256) h[i] = 0;
    __syncthreads();
    for (int e = blockIdx.x * 256 + threadIdx.x; e < NE; e += SBLK * 256)
        atomicAdd(&h[col[e] >> BSH], 1);
    __syncthreads();
    for (int i = threadIdx.x; i < NBUCK; i += 256)
        if (h[i]) atomicAdd(&cnt[i], h[i]);
}

// ---------------------------------------------------------------------------
// K_b: exclusive scan of 782 bucket counts (one small block). Writes gbase
// (mutable reservation cursors) and H0 (immutable segment bounds).
// ---------------------------------------------------------------------------
__global__ __launch_bounds__(1024) void bscan_kernel(const int* __restrict__ cnt,
                                                     int* __restrict__ gbase,
                                                     int* __restrict__ H0) {
    __shared__ int s[1024];
    const int t = threadIdx.x;
    const int v = (t < NBUCK) ? cnt[t] : 0;
    s[t] = v;
    __syncthreads();
    for (int off = 1; off < 1024; off <<= 1) {
        int x = (t >= off) ? s[t - off] : 0;
        __syncthreads();
        s[t] += x;
        __syncthreads();
    }
    const int excl = s[t] - v;
    if (t < NBUCK) { gbase[t] = excl; H0[t] = excl; }
    if (t == 0) H0[NBUCK] = NE;
}

// ---------------------------------------------------------------------------
// K_c: scatter into bucket-contiguous runs. Each block reserves a run per
// bucket via one global atomicAdd, then scatters with LDS counters.
// Payload: x = (col&127) | (row<<7) (17+7=24 bits), y = ew bits.
// ---------------------------------------------------------------------------
__global__ __launch_bounds__(256) void bscatter_kernel(const int* __restrict__ ei,
                                                       const float* __restrict__ ew,
                                                       int* __restrict__ gbase,
                                                       int2* __restrict__ mid) {
    __shared__ int h[NBUCK];
    __shared__ int rbase[NBUCK];
    for (int i = threadIdx.x; i < NBUCK; i += 256) h[i] = 0;
    __syncthreads();
    for (int e = blockIdx.x * 256 + threadIdx.x; e < NE; e += SBLK * 256)
        atomicAdd(&h[ei[NE + e] >> BSH], 1);
    __syncthreads();
    for (int i = threadIdx.x; i < NBUCK; i += 256) {
        const int c0 = h[i];
        rbase[i] = c0 ? atomicAdd(&gbase[i], c0) : 0;
        h[i] = 0;   // reuse as running counter
    }
    __syncthreads();
    for (int e = blockIdx.x * 256 + threadIdx.x; e < NE; e += SBLK * 256) {
        const int c = ei[NE + e];
        const int r = ei[e];
        const float w = ew[e];
        const int b = c >> BSH;
        const int pos = rbase[b] + atomicAdd(&h[b], 1);
        mid[pos] = make_int2((c & (BCOLS - 1)) | (r << BSH), __float_as_int(w));
    }
}

// ---------------------------------------------------------------------------
// K_d: fused per-bucket degree + row packing.
//   dinv = rsqrt(deg + 1);  pack[r][0..20] = dinv[r]*{ux[r],mx[r]},
//   pack[r][21] = dinv[r], rows 96 B / 16B-aligned.
// ---------------------------------------------------------------------------
__global__ __launch_bounds__(256) void bdeg_pack_kernel(const int2* __restrict__ mid,
                                                        const int* __restrict__ H0,
                                                        const float* __restrict__ ux,
                                                        const float* __restrict__ mx,
                                                        float* __restrict__ pack) {
    __shared__ float dl[BCOLS];
    const int b = blockIdx.x;
    const int t = threadIdx.x;
    if (t < BCOLS) dl[t] = 0.f;
    __syncthreads();
    const int start = H0[b];
    const int end = H0[b + 1];
    for (int i = start + t; i < end; i += 256) {
        const int2 p = mid[i];
        atomicAdd(&dl[p.x & (BCOLS - 1)], __int_as_float(p.y));
    }
    __syncthreads();
    if (t < BCOLS) {
        const int c = b * BCOLS + t;
        if (c < NN) dl[t] = rsqrtf(dl[t] + 1.0f);
    }
    __syncthreads();
    const size_t obase = (size_t)b * BCOLS * 24;
    for (int f = t; f < BCOLS * 24; f += 256) {
        const int rl = f / 24;
        const int m = f - rl * 24;
        const int r = b * BCOLS + rl;
        if (r < NN) {
            const float d = dl[rl];
            float v;
            if (m < 3) v = d * ux[(size_t)r * 3 + m];
            else if (m < 21) v = d * mx[(size_t)r * 18 + (m - 3)];
            else if (m == 21) v = d;
            else v = 0.f;
            pack[obase + f] = v;
        }
    }
}

// ---------------------------------------------------------------------------
// K_e: per-bucket counting sort of PAYLOADS into LDS (no index indirection),
// then 2-threads-per-col register aggregation + fused MLP (k split 2-way).
// 256 threads / 128-col bucket; 782 blocks (~3/CU).
// ---------------------------------------------------------------------------
__global__ __launch_bounds__(256) void bagg_mlp_kernel(const int2* __restrict__ mid,
                                                       const int* __restrict__ H0,
                                                       const float* __restrict__ pack,
                                                       const float* __restrict__ Mt,
                                                       const float* __restrict__ b2,
                                                       float* __restrict__ out) {
    __shared__ int2 smid[CAP];          // 16 KB: sorted payloads
    __shared__ int cbase[BCOLS];        // inclusive scan of counts
    __shared__ int ccur[BCOLS];         // running scatter pointers
    __shared__ float sp[BCOLS][21];     // 10.75 KB: half-1 partials / combined s21
    __shared__ float po[BCOLS];         // MLP half-1 partials

    const int b = blockIdx.x;
    const int t = threadIdx.x;
    const int col = t & (BCOLS - 1);
    const int hf = t >> 7;              // 0 or 1
    const int start = H0[b];
    const int end = H0[b + 1];
    const int seg = end - start;
    const int segc = seg < CAP ? seg : CAP;

    // phase 1: per-col counts (coalesced mid read #1)
    if (t < BCOLS) ccur[t] = 0;
    __syncthreads();
    for (int i = t; i < segc; i += 256)
        atomicAdd(&ccur[mid[start + i].x & (BCOLS - 1)], 1);
    __syncthreads();

    // phase 2: inclusive scan of 128 counts (threads 0..127, full-block barriers)
    int myc = 0;
    if (t < BCOLS) { myc = ccur[t]; cbase[t] = myc; }
    __syncthreads();
    for (int off = 1; off < BCOLS; off <<= 1) {
        int x = 0;
        if (t < BCOLS && t >= off) x = cbase[t - off];
        __syncthreads();
        if (t < BCOLS) cbase[t] += x;
        __syncthreads();
    }
    if (t < BCOLS) ccur[t] = cbase[t] - myc;   // exclusive base = scatter ptr
    __syncthreads();

    // phase 3: scatter payloads into LDS sorted order (coalesced mid read #2)
    for (int i = t; i < segc; i += 256) {
        const int2 p = mid[start + i];
        const int pos = atomicAdd(&ccur[p.x & (BCOLS - 1)], 1);
        smid[pos] = p;
    }
    __syncthreads();

    // phase 4: register aggregation, 2 threads per col (hf picks odd/even edges)
    float s21[21];
#pragma unroll
    for (int m = 0; m < 21; m++) s21[m] = 0.f;

    const int s0 = (col == 0) ? 0 : cbase[col - 1];
    const int s1 = cbase[col];
#pragma unroll 2
    for (int i = s0 + hf; i < s1; i += 2) {
        const int2 p = smid[i];
        const unsigned row = ((unsigned)p.x) >> BSH;
        const float w = __int_as_float(p.y);
        const float4* pr = (const float4*)(pack + (size_t)row * 24);
        const float4 v0 = pr[0];
        const float4 v1 = pr[1];
        const float4 v2 = pr[2];
        const float4 v3 = pr[3];
        const float4 v4 = pr[4];
        const float4 v5 = pr[5];
        s21[0]  = fmaf(w, v0.x, s21[0]);
        s21[1]  = fmaf(w, v0.y, s21[1]);
        s21[2]  = fmaf(w, v0.z, s21[2]);
        s21[3]  = fmaf(w, v0.w, s21[3]);
        s21[4]  = fmaf(w, v1.x, s21[4]);
        s21[5]  = fmaf(w, v1.y, s21[5]);
        s21[6]  = fmaf(w, v1.z, s21[6]);
        s21[7]  = fmaf(w, v1.w, s21[7]);
        s21[8]  = fmaf(w, v2.x, s21[8]);
        s21[9]  = fmaf(w, v2.y, s21[9]);
        s21[10] = fmaf(w, v2.z, s21[10]);
        s21[11] = fmaf(w, v2.w, s21[11]);
        s21[12] = fmaf(w, v3.x, s21[12]);
        s21[13] = fmaf(w, v3.y, s21[13]);
        s21[14] = fmaf(w, v3.z, s21[14]);
        s21[15] = fmaf(w, v3.w, s21[15]);
        s21[16] = fmaf(w, v4.x, s21[16]);
        s21[17] = fmaf(w, v4.y, s21[17]);
        s21[18] = fmaf(w, v4.z, s21[18]);
        s21[19] = fmaf(w, v4.w, s21[19]);
        s21[20] = fmaf(w, v5.x, s21[20]);
    }

    // combine halves: hf=1 publishes, hf=0 owns the column
    if (hf) {
#pragma unroll
        for (int m = 0; m < 21; m++) sp[col][m] = s21[m];
    }
    __syncthreads();

    const int c = b * BCOLS + col;
    if (!hf) {
#pragma unroll
        for (int m = 0; m < 21; m++) s21[m] += sp[col][m];
        // overflow edges beyond CAP (statistically never; correctness fallback)
        if (seg > CAP) {
            for (int i = CAP; i < seg; i++) {
                const int2 p = mid[start + i];
                if ((p.x & (BCOLS - 1)) == col) {
                    const unsigned row = ((unsigned)p.x) >> BSH;
                    const float w = __int_as_float(p.y);
                    const float* pr = pack + (size_t)row * 24;
#pragma unroll
                    for (int m = 0; m < 21; m++) s21[m] = fmaf(w, pr[m], s21[m]);
                }
            }
        }
        if (c < NN) {
            const float4* pr = (const float4*)(pack + (size_t)c * 24);
            const float4 v0 = pr[0];
            const float4 v1 = pr[1];
            const float4 v2 = pr[2];
            const float4 v3 = pr[3];
            const float4 v4 = pr[4];
            const float4 v5 = pr[5];
            const float d = v5.y;          // dinv[c]
            s21[0]  = d * (s21[0]  + v0.x);
            s21[1]  = d * (s21[1]  + v0.y);
            s21[2]  = d * (s21[2]  + v0.z);
            s21[3]  = d * (s21[3]  + v0.w);
            s21[4]  = d * (s21[4]  + v1.x);
            s21[5]  = d * (s21[5]  + v1.y);
            s21[6]  = d * (s21[6]  + v1.z);
            s21[7]  = d * (s21[7]  + v1.w);
            s21[8]  = d * (s21[8]  + v2.x);
            s21[9]  = d * (s21[9]  + v2.y);
            s21[10] = d * (s21[10] + v2.z);
            s21[11] = d * (s21[11] + v2.w);
            s21[12] = d * (s21[12] + v3.x);
            s21[13] = d * (s21[13] + v3.y);
            s21[14] = d * (s21[14] + v3.z);
            s21[15] = d * (s21[15] + v3.w);
            s21[16] = d * (s21[16] + v4.x);
            s21[17] = d * (s21[17] + v4.y);
            s21[18] = d * (s21[18] + v4.z);
            s21[19] = d * (s21[19] + v4.w);
            s21[20] = d * (s21[20] + v5.x);
        }
#pragma unroll
        for (int m = 0; m < 21; m++) sp[col][m] = s21[m];
    }
    __syncthreads();
    if (hf) {
#pragma unroll
        for (int m = 0; m < 21; m++) s21[m] = sp[col][m];
    }

    // fused MLP, k split across halves (hf wave-uniform: waves are 64 lanes)
    float o = 0.f;
    const int k0 = hf * 64;
#pragma unroll 4
    for (int k = k0; k < k0 + 64; k++) {
        const float* r = Mt + k * 24;
        float hsum = r[21];
#pragma unroll
        for (int m = 0; m < 21; m++) hsum = fmaf(s21[m], r[m], hsum);
        o = fmaf(fmaxf(hsum, 0.f), r[22], o);
    }
    if (hf) po[col] = o;
    __syncthreads();
    if (!hf && c < NN) out[c] = o + po[col] + b2[0];
}

// ===========================================================================
extern "C" void kernel_launch(void* const* d_in, const int* in_sizes, int n_in,
                              void* d_out, int out_size, void* d_ws, size_t ws_size,
                              hipStream_t stream) {
    const float* ux = (const float*)d_in[0];   // user_x  [N,3]
    const float* mx = (const float*)d_in[1];   // movie_x [N,18]
    const int* ei = (const int*)d_in[2];       // edge_index [2,E]
    const float* ew = (const float*)d_in[3];   // edge_attr [E]
    const float* Wu = (const float*)d_in[4];   // [3,64]
    const float* bu = (const float*)d_in[5];   // [64]
    const float* Wm = (const float*)d_in[6];   // [18,64]
    const float* bm = (const float*)d_in[7];   // [64]
    const float* W1 = (const float*)d_in[8];   // [128,128]
    const float* b1 = (const float*)d_in[9];   // [128]
    const float* W2 = (const float*)d_in[10];  // [128,1]
    const float* b2 = (const float*)d_in[11];  // [1]
    float* out = (float*)d_out;

    char* ws = (char*)d_ws;
    int*   cnt   = (int*)ws;                   // @0       3,128 B
    int*   gbase = (int*)(ws + 4096);          // @4096    3,128 B
    int*   H0    = (int*)(ws + 8192);          // @8192    3,132 B
    float* Mt    = (float*)(ws + 12288);       // @12288   12,288 B
    float* pack  = (float*)(ws + 24576);       // @24576   9,600,000 B (16B-aligned)
    int2*  mid   = (int2*)(ws + 9624576);      // @9624576 8,000,000 B
    // total ~17.6 MB

    fuse_kernel<<<1, 128, 0, stream>>>(Wu, bu, Wm, bm, W1, b1, W2, Mt, cnt);
    bcnt_kernel<<<SBLK, 256, 0, stream>>>(ei + NE, cnt);
    bscan_kernel<<<1, 1024, 0, stream>>>(cnt, gbase, H0);
    bscatter_kernel<<<SBLK, 256, 0, stream>>>(ei, ew, gbase, mid);
    bdeg_pack_kernel<<<NBUCK, 256, 0, stream>>>(mid, H0, ux, mx, pack);
    bagg_mlp_kernel<<<NBUCK, 256, 0, stream>>>(mid, H0, pack, Mt, b2, out);
}